// Round 2
// baseline (313.635 us; speedup 1.0000x reference)
//
#include <hip/hip_runtime.h>

#define NCLS  32
#define SOS   30
#define EOS   31
#define LOG2E 1.4426950408889634f
#define LN2   0.6931471805599453f

// LDS staging ring (per wave): 16 slots of 2304 B
//   slot layout: [0..1023] feats lo16B/lane, [1024..2047] feats hi16B/lane,
//                [2048..2303] mask 4B/lane
#define RING_D  16
#define SLOT_B  2304
#define RING_B  (RING_D * SLOT_B)

typedef __attribute__((ext_vector_type(8))) short short8;
typedef __attribute__((ext_vector_type(4))) float f32x4;

__device__ __forceinline__ uint32_t rne_bf16(float x) {
    uint32_t u = __float_as_uint(x);
    return (u + 0x7fffu + ((u >> 16) & 1u)) >> 16;
}

// Fire-and-forget global->LDS DMA. No VGPR destination => the compiler cannot
// sink these loads; pipeline depth is enforced by hand-counted vmcnt below.
// LDS dest is wave-uniform base; HW writes lane L at base + L*size.
// Global src is per-lane (each lane fetches exactly the bytes it will read back).
__device__ __forceinline__ void dma16(const float* g, char* l) {
    __builtin_amdgcn_global_load_lds((const __attribute__((address_space(1))) void*)g,
                                     (__attribute__((address_space(3))) void*)l, 16, 0, 0);
}
__device__ __forceinline__ void dma4(const float* g, char* l) {
    __builtin_amdgcn_global_load_lds((const __attribute__((address_space(1))) void*)g,
                                     (__attribute__((address_space(3))) void*)l, 4, 0, 0);
}

#define WAITV45 asm volatile("s_waitcnt vmcnt(45)" ::: "memory")
#define WAITV42 asm volatile("s_waitcnt vmcnt(42)" ::: "memory")

// Meet-in-the-middle MFMA CRF forward, linear domain.
//   out_b = ln( u^T M_S ... M_1 v0 ),  M_t = m_t ? diag(ef_t) X : I.
// Wave 0 (fwd): E_t = M_t E_{t-1}, rows 0..H-1.
// Wave 1 (bwd): wtil recurrence, rows S-1..H. Combine via LDS.
//
// Round 7 (this version): keep 16 real batches per wave (round 6's 8x work
// reduction) but fix the latency exposure that killed round 6: VGPR prefetch
// rings get re-scheduled by the compiler (load->use distance collapsed to ~1
// step, ~800cy stall/step, VALUBusy 6%). Replace with global_load_lds DMA
// into a wave-PRIVATE 16-slot LDS ring + hand-counted s_waitcnt vmcnt(42)
// (never 0, no barriers anywhere in the loop) — the m201-proven counted-vmcnt
// mechanism. ~14 slots (33KB/wave) stay in flight. ds_read latency hidden by
// 1-slot read-ahead into alternating raw reg buffers (static indexing).
__global__ __launch_bounds__(128, 1) void crf_fwd(const float* __restrict__ feats,
                                                  const float* __restrict__ mask,
                                                  const float* __restrict__ trans,
                                                  float* __restrict__ out,
                                                  int S, int B) {
    __shared__ float mxs[2][NCLS];                // [0]=row max (fwd), [1]=col max (bwd)
    __shared__ __align__(16) float wsh[16][NCLS]; // combine vectors, one row per batch col
    __shared__ float wsc[16];                     // combine scalars
    __shared__ __align__(16) char ring[2][RING_B];

    const int tid  = threadIdx.x;
    const int wid  = tid >> 6;        // 0 = forward wave, 1 = backward wave
    const int lane = tid & 63;
    const int q  = lane >> 4;
    const int n0 = lane & 15;
    const int k0 = q * 8;
    const int b  = blockIdx.x * 16 + n0;   // 16 real batches per block, one per column
    const int bb = (b < B) ? b : (B - 1);
    const int l16 = lane << 4;
    const int l4  = lane << 2;
    char* const slotbase = &ring[wid][0];

    // ---- per-class normalizers: fwd = row max, bwd = col max (log2-scaled) ----
    if (lane < NCLS) {
        float mx = -3.4e38f;
        #pragma unroll
        for (int k = 0; k < NCLS; ++k)
            mx = fmaxf(mx, wid ? trans[k * NCLS + lane] : trans[lane * NCLS + k]);
        mxs[wid][lane] = mx * LOG2E;
    }
    __builtin_amdgcn_wave_barrier();
    const float* mx_ = mxs[wid];

    // ---- A fragments, class-permuted so D-layout == next step's B-layout ----
    const int c1 = ((n0 >> 2) << 3) | (n0 & 3);
    const int c2 = c1 + 4;
    const float nc1 = mx_[c1], nc2 = mx_[c2];
    union { uint32_t u[4]; short8 s; } a1u, a2u;
    #pragma unroll
    for (int j2 = 0; j2 < 4; ++j2) {
        const int ka = k0 + 2 * j2, kb = ka + 1;
        float f0 = __builtin_amdgcn_exp2f((wid ? trans[ka*NCLS + c1] : trans[c1*NCLS + ka]) * LOG2E - nc1);
        float f1 = __builtin_amdgcn_exp2f((wid ? trans[kb*NCLS + c1] : trans[c1*NCLS + kb]) * LOG2E - nc1);
        a1u.u[j2] = rne_bf16(f0) | (rne_bf16(f1) << 16);
        float g0 = __builtin_amdgcn_exp2f((wid ? trans[ka*NCLS + c2] : trans[c2*NCLS + ka]) * LOG2E - nc2);
        float g1 = __builtin_amdgcn_exp2f((wid ? trans[kb*NCLS + c2] : trans[c2*NCLS + kb]) * LOG2E - nc2);
        a2u.u[j2] = rne_bf16(g0) | (rne_bf16(g1) << 16);
    }
    const short8 a1 = a1u.s, a2 = a2u.s;

    // ---- conversion biases for this lane's classes k0..k0+7 ----
    const float mtAx = mx_[k0+0] - 6.f, mtAy = mx_[k0+1] - 6.f;
    const float mtAz = mx_[k0+2] - 6.f, mtAw = mx_[k0+3] - 6.f;
    const float mtBx = mx_[k0+4] - 6.f, mtBy = mx_[k0+5] - 6.f;
    const float mtBz = mx_[k0+6] - 6.f, mtBw = mx_[k0+7] - 6.f;

    // ---- state init (identical for every batch column) ----
    float E1x = 0.f, E1y = 0.f, E1z = 0.f, E1w = 0.f;
    float E2x = 0.f, E2y = 0.f, E2z = 0.f, E2w = 0.f;
    if (wid == 0) {
        if (q == 3) E2z = 1.0f;       // SOS = 30 = 8*3+6
    } else {
        E1x = __builtin_amdgcn_exp2f(trans[EOS*NCLS + k0+0] * LOG2E - mx_[k0+0]);
        E1y = __builtin_amdgcn_exp2f(trans[EOS*NCLS + k0+1] * LOG2E - mx_[k0+1]);
        E1z = __builtin_amdgcn_exp2f(trans[EOS*NCLS + k0+2] * LOG2E - mx_[k0+2]);
        E1w = __builtin_amdgcn_exp2f(trans[EOS*NCLS + k0+3] * LOG2E - mx_[k0+3]);
        E2x = __builtin_amdgcn_exp2f(trans[EOS*NCLS + k0+4] * LOG2E - mx_[k0+4]);
        E2y = __builtin_amdgcn_exp2f(trans[EOS*NCLS + k0+5] * LOG2E - mx_[k0+5]);
        E2z = __builtin_amdgcn_exp2f(trans[EOS*NCLS + k0+6] * LOG2E - mx_[k0+6]);
        E2w = __builtin_amdgcn_exp2f(trans[EOS*NCLS + k0+7] * LOG2E - mx_[k0+7]);
    }
    float C = 0.f, cnt = 0.f;

    // ---- direction setup ----
    const long long fstep = (long long)B * NCLS;
    const int Hf = (S + 1) >> 1;
    const int H  = wid ? (S - Hf) : Hf;
    const int r0 = wid ? (S - 1) : 0;
    const long long dstep = wid ? -fstep : fstep;
    const long long mstep = wid ? -(long long)B : (long long)B;
    const float* fbase = feats + (long long)r0 * fstep + (long long)bb * NCLS + k0;
    const float* mbase = mask + (long long)r0 * B + bb;

// stage time TS into ring slot SLOT (3 DMAs; LDS dest base is wave-uniform)
#define STAGE(TS, SLOT) {                                                    \
        const float* _gf = fbase + (long long)(TS) * dstep;                  \
        const float* _gm = mbase + (long long)(TS) * mstep;                  \
        char* _l = slotbase + (SLOT) * SLOT_B;                               \
        dma16(_gf,     _l);                                                  \
        dma16(_gf + 4, _l + 1024);                                           \
        dma4 (_gm,     _l + 2048);                                           \
    }

// read ring slot SLOT back into raw regs (each lane reads its own bytes)
#define READSLOT(SLOT, Rf1, Rf2, Rm) {                                       \
        const char* _l = slotbase + (SLOT) * SLOT_B;                         \
        Rf1 = *(const f32x4*)(_l + l16);                                     \
        Rf2 = *(const f32x4*)(_l + 1024 + l16);                              \
        Rm  = *(const float*)(_l + 2048 + l4);                               \
    }

#define CONV(Rf1, Rf2, Rm, Ea, Eb, Md) {                                     \
        Ea.x = __builtin_amdgcn_exp2f(fmaf(Rf1.x, LOG2E, mtAx));             \
        Ea.y = __builtin_amdgcn_exp2f(fmaf(Rf1.y, LOG2E, mtAy));             \
        Ea.z = __builtin_amdgcn_exp2f(fmaf(Rf1.z, LOG2E, mtAz));             \
        Ea.w = __builtin_amdgcn_exp2f(fmaf(Rf1.w, LOG2E, mtAw));             \
        Eb.x = __builtin_amdgcn_exp2f(fmaf(Rf2.x, LOG2E, mtBx));             \
        Eb.y = __builtin_amdgcn_exp2f(fmaf(Rf2.y, LOG2E, mtBy));             \
        Eb.z = __builtin_amdgcn_exp2f(fmaf(Rf2.z, LOG2E, mtBz));             \
        Eb.w = __builtin_amdgcn_exp2f(fmaf(Rf2.w, LOG2E, mtBw));             \
        Md = Rm;                                                             \
    }

#define RENORM_E {                                                           \
        float _Dv = __shfl(E1x, n0, 64);      /* class 0 of this column */   \
        uint32_t _eb = (__float_as_uint(_Dv) >> 23) & 0xffu;                 \
        C += (float)((int)_eb - 127);                                        \
        float _sc = __uint_as_float((254u - _eb) << 23);                     \
        E1x *= _sc; E1y *= _sc; E1z *= _sc; E1w *= _sc;                      \
        E2x *= _sc; E2y *= _sc; E2z *= _sc; E2w *= _sc;                      \
    }

// fwd step: D = A*pack(E); E' = sel(ef .* D, E)
#define STEPF(EFa, EFb, EM, RN) {                                            \
        uint32_t p0 = __builtin_amdgcn_perm(__float_as_uint(E1y), __float_as_uint(E1x), 0x07060302u); \
        uint32_t p1 = __builtin_amdgcn_perm(__float_as_uint(E1w), __float_as_uint(E1z), 0x07060302u); \
        uint32_t p2 = __builtin_amdgcn_perm(__float_as_uint(E2y), __float_as_uint(E2x), 0x07060302u); \
        uint32_t p3 = __builtin_amdgcn_perm(__float_as_uint(E2w), __float_as_uint(E2z), 0x07060302u); \
        union { uint32_t u[4]; short8 s; } _bu;                              \
        _bu.u[0] = p0; _bu.u[1] = p1; _bu.u[2] = p2; _bu.u[3] = p3;          \
        const f32x4 _z = {0.f, 0.f, 0.f, 0.f};                               \
        f32x4 _d1 = __builtin_amdgcn_mfma_f32_16x16x32_bf16(a1, _bu.s, _z, 0, 0, 0); \
        f32x4 _d2 = __builtin_amdgcn_mfma_f32_16x16x32_bf16(a2, _bu.s, _z, 0, 0, 0); \
        const bool _s = (EM != 0.0f);                                        \
        E1x = _s ? _d1[0] * EFa.x : E1x;  E1y = _s ? _d1[1] * EFa.y : E1y;   \
        E1z = _s ? _d1[2] * EFa.z : E1z;  E1w = _s ? _d1[3] * EFa.w : E1w;   \
        E2x = _s ? _d2[0] * EFb.x : E2x;  E2y = _s ? _d2[1] * EFb.y : E2y;   \
        E2z = _s ? _d2[2] * EFb.z : E2z;  E2w = _s ? _d2[3] * EFb.w : E2w;   \
        cnt += EM;                                                           \
        if (RN) RENORM_E                                                     \
    }

// bwd step: t = ef .* w; D = A*pack(t); w' = sel(D, w)
#define STEPB(EFa, EFb, EM, RN) {                                            \
        float t1x = E1x * EFa.x, t1y = E1y * EFa.y, t1z = E1z * EFa.z, t1w = E1w * EFa.w; \
        float t2x = E2x * EFb.x, t2y = E2y * EFb.y, t2z = E2z * EFb.z, t2w = E2w * EFb.w; \
        uint32_t p0 = __builtin_amdgcn_perm(__float_as_uint(t1y), __float_as_uint(t1x), 0x07060302u); \
        uint32_t p1 = __builtin_amdgcn_perm(__float_as_uint(t1w), __float_as_uint(t1z), 0x07060302u); \
        uint32_t p2 = __builtin_amdgcn_perm(__float_as_uint(t2y), __float_as_uint(t2x), 0x07060302u); \
        uint32_t p3 = __builtin_amdgcn_perm(__float_as_uint(t2w), __float_as_uint(t2z), 0x07060302u); \
        union { uint32_t u[4]; short8 s; } _bu;                              \
        _bu.u[0] = p0; _bu.u[1] = p1; _bu.u[2] = p2; _bu.u[3] = p3;          \
        const f32x4 _z = {0.f, 0.f, 0.f, 0.f};                               \
        f32x4 _d1 = __builtin_amdgcn_mfma_f32_16x16x32_bf16(a1, _bu.s, _z, 0, 0, 0); \
        f32x4 _d2 = __builtin_amdgcn_mfma_f32_16x16x32_bf16(a2, _bu.s, _z, 0, 0, 0); \
        const bool _s = (EM != 0.0f);                                        \
        E1x = _s ? _d1[0] : E1x;  E1y = _s ? _d1[1] : E1y;                   \
        E1z = _s ? _d1[2] : E1z;  E1w = _s ? _d1[3] : E1w;                   \
        E2x = _s ? _d2[0] : E2x;  E2y = _s ? _d2[1] : E2y;                   \
        E2z = _s ? _d2[2] : E2z;  E2w = _s ? _d2[3] : E2w;                   \
        cnt += EM;                                                           \
        if (RN) RENORM_E                                                     \
    }

// one pipelined iteration: stage t+15 | wait 42 | read-ahead raw(t+1) into F |
// STEP consumes e=conv(t-1) | CONV raw(t)=U -> e
#define PIPEITER(T, U1, U2, Um, F1, F2, Fm, RN, STEPM) {                     \
        { const int _ts = ((T) + RING_D - 1 < H) ? ((T) + RING_D - 1) : (H - 1); \
          STAGE(_ts, ((T) - 1) & (RING_D - 1)) }                             \
        WAITV42;                                                             \
        { const int _tr = ((T) + 1 < H) ? ((T) + 1) : (H - 1);               \
          READSLOT(_tr & (RING_D - 1), F1, F2, Fm) }                         \
        STEPM(e1, e2, em, RN)                                                \
        CONV(U1, U2, Um, e1, e2, em);                                        \
    }

#define PIPELINE(STEPM) {                                                    \
        f32x4 e1, e2; float em;                                              \
        f32x4 rA1, rA2, rB1, rB2; float rAm, rBm;                            \
        /* prologue: stage times 0..15 (clamped), 48 DMAs in flight */       \
        _Pragma("unroll")                                                    \
        for (int s = 0; s < RING_D; ++s) {                                   \
            const int _ps = (s < H) ? s : (H - 1);                           \
            STAGE(_ps, s)                                                    \
        }                                                                    \
        WAITV45;                         /* time 0 landed */                 \
        READSLOT(0, rA1, rA2, rAm)                                           \
        WAITV42;                         /* time 1 landed */                 \
        { const int _t1 = (1 < H) ? 1 : 0;                                   \
          READSLOT(_t1, rB1, rB2, rBm) }                                     \
        CONV(rA1, rA2, rAm, e1, e2, em);                                     \
        int t = 1;                                                           \
        for (; t + 3 < H; t += 4) {                                          \
            PIPEITER(t+0, rB1, rB2, rBm, rA1, rA2, rAm, false, STEPM)        \
            PIPEITER(t+1, rA1, rA2, rAm, rB1, rB2, rBm, false, STEPM)        \
            PIPEITER(t+2, rB1, rB2, rBm, rA1, rA2, rAm, false, STEPM)        \
            PIPEITER(t+3, rA1, rA2, rAm, rB1, rB2, rBm, true,  STEPM)        \
        }                                                                    \
        for (; t < H; ++t) {             /* <=3 leftover, fresh LDS reads */ \
            { const int _ts = (t + RING_D - 1 < H) ? (t + RING_D - 1) : (H - 1); \
              STAGE(_ts, (t - 1) & (RING_D - 1)) }                           \
            WAITV42;                                                         \
            f32x4 x1, x2; float xm;                                          \
            READSLOT(t & (RING_D - 1), x1, x2, xm)                           \
            STEPM(e1, e2, em, true)                                          \
            CONV(x1, x2, xm, e1, e2, em);                                    \
        }                                                                    \
        STEPM(e1, e2, em, true)          /* final step: time H-1 */          \
    }

    if (H > 0) {
        if (wid == 0) { PIPELINE(STEPF) } else { PIPELINE(STEPB) }
    }

    // ---- combine: bwd publishes wtil*2^cms + scalar; fwd dots with E ----
    if (wid == 1) {
        wsh[n0][k0+0] = E1x * __builtin_amdgcn_exp2f(mx_[k0+0]);
        wsh[n0][k0+1] = E1y * __builtin_amdgcn_exp2f(mx_[k0+1]);
        wsh[n0][k0+2] = E1z * __builtin_amdgcn_exp2f(mx_[k0+2]);
        wsh[n0][k0+3] = E1w * __builtin_amdgcn_exp2f(mx_[k0+3]);
        wsh[n0][k0+4] = E2x * __builtin_amdgcn_exp2f(mx_[k0+4]);
        wsh[n0][k0+5] = E2y * __builtin_amdgcn_exp2f(mx_[k0+5]);
        wsh[n0][k0+6] = E2z * __builtin_amdgcn_exp2f(mx_[k0+6]);
        wsh[n0][k0+7] = E2w * __builtin_amdgcn_exp2f(mx_[k0+7]);
        if (q == 0) wsc[n0] = C + 6.0f * cnt;
    }
    __syncthreads();
    if (wid == 0) {
        const f32x4 wa = *(const f32x4*)&wsh[n0][k0];
        const f32x4 wb = *(const f32x4*)&wsh[n0][k0 + 4];
        float dot = E1x * wa.x + E1y * wa.y + E1z * wa.z + E1w * wa.w
                  + E2x * wb.x + E2y * wb.y + E2z * wb.z + E2w * wb.w;
        dot += __shfl_xor(dot, 16, 64);
        dot += __shfl_xor(dot, 32, 64);
        if (q == 0 && b < B) {
            out[b] = LN2 * (C + 6.0f * cnt + wsc[n0] + __builtin_amdgcn_logf(dot));
        }
    }
#undef STAGE
#undef READSLOT
#undef CONV
#undef RENORM_E
#undef STEPF
#undef STEPB
#undef PIPEITER
#undef PIPELINE
}

extern "C" void kernel_launch(void* const* d_in, const int* in_sizes, int n_in,
                              void* d_out, int out_size, void* d_ws, size_t ws_size,
                              hipStream_t stream) {
    const float* feats = (const float*)d_in[0];
    const float* mask  = (const float*)d_in[1];
    const float* trans = (const float*)d_in[2];
    float* out = (float*)d_out;

    const int B = out_size;            // batch  (2048)
    const int S = in_sizes[1] / B;     // seq_len (512)

    dim3 block(128);                   // wave 0 = fwd, wave 1 = bwd
    dim3 grid((B + 15) / 16);          // 16 real batches per block -> 128 blocks
    hipLaunchKernelGGL(crf_fwd, grid, block, 0, stream, feats, mask, trans, out, S, B);
}

// Round 4
// 193.684 us; speedup vs baseline: 1.6193x; 1.6193x over previous
//
#include <hip/hip_runtime.h>

#define NCLS  32
#define SOS   30
#define EOS   31
#define LOG2E 1.4426950408889634f
#define LN2   0.6931471805599453f

typedef __attribute__((ext_vector_type(8))) short short8;
typedef __attribute__((ext_vector_type(4))) float f32x4;

__device__ __forceinline__ uint32_t rne_bf16(float x) {
    uint32_t u = __float_as_uint(x);
    return (u + 0x7fffu + ((u >> 16) & 1u)) >> 16;
}

// Meet-in-the-middle MFMA CRF forward, linear domain.
//   out_b = ln( u^T M_S ... M_1 v0 ),  M_t = m_t ? diag(ef_t) X : I.
// Wave 0 (fwd): E_t = M_t E_{t-1}, rows 0..H-1.
// Wave 1 (bwd): wtil recurrence, rows S-1..H. Combine via LDS.
//
// Round 9 (this version) = round 8 with the asm register-hazard fixed:
// round 8's ISSUE3 used plain "=v" outputs in a multi-instruction asm block,
// letting the allocator overlap load destinations with the address VGPRs
// (%3/%5) that later instructions still read; async data-return then
// corrupted addresses -> wild loads -> page fault -> container abort.
// Fix: "=&v" EARLY-CLOBBER on all outputs (allocator keeps outputs disjoint
// from all inputs).
//
// Mechanism recap (rounds 6/7 post-mortems):
//  - C-level VGPR ring: compiler re-schedules, load->use collapses (~1030cy/step)
//  - LDS DMA ring: SIInsertWaitcnts inserts vmcnt(0) before every ds_read
//    it can't prove independent (~1680cy/step)
//  - inline-asm reg ring (this): invisible to the waitcnt pass, immovable
//    among volatile asm; only waits are our counted s_waitcnt vmcnt(21)
//    (+ sched_barrier(0) per rule #18). 8 named slots (static indexing,
//    rule #20), 3 loads/slot, 24 outstanding, load->use ~7.3 steps (~1400cy)
//    > 900cy HBM latency. No other VMEM in the loop (prologue trans-load
//    stragglers only inflate the count -> waits get stricter, still safe).
__global__ __launch_bounds__(128, 1) void crf_fwd(const float* __restrict__ feats,
                                                  const float* __restrict__ mask,
                                                  const float* __restrict__ trans,
                                                  float* __restrict__ out,
                                                  int S, int B) {
    __shared__ float mxs[2][NCLS];                // [0]=row max (fwd), [1]=col max (bwd)
    __shared__ __align__(16) float wsh[16][NCLS]; // combine vectors, one row per batch col
    __shared__ float wsc[16];                     // combine scalars

    const int tid  = threadIdx.x;
    const int wid  = tid >> 6;        // 0 = forward wave, 1 = backward wave
    const int lane = tid & 63;
    const int q  = lane >> 4;
    const int n0 = lane & 15;
    const int k0 = q * 8;
    const int b  = blockIdx.x * 16 + n0;   // 16 real batches per block, one per column
    const int bb = (b < B) ? b : (B - 1);

    // ---- per-class normalizers: fwd = row max, bwd = col max (log2-scaled) ----
    if (lane < NCLS) {
        float mx = -3.4e38f;
        #pragma unroll
        for (int k = 0; k < NCLS; ++k)
            mx = fmaxf(mx, wid ? trans[k * NCLS + lane] : trans[lane * NCLS + k]);
        mxs[wid][lane] = mx * LOG2E;
    }
    __builtin_amdgcn_wave_barrier();
    const float* mx_ = mxs[wid];

    // ---- A fragments, class-permuted so D-layout == next step's B-layout ----
    const int c1 = ((n0 >> 2) << 3) | (n0 & 3);
    const int c2 = c1 + 4;
    const float nc1 = mx_[c1], nc2 = mx_[c2];
    union { uint32_t u[4]; short8 s; } a1u, a2u;
    #pragma unroll
    for (int j2 = 0; j2 < 4; ++j2) {
        const int ka = k0 + 2 * j2, kb = ka + 1;
        float f0 = __builtin_amdgcn_exp2f((wid ? trans[ka*NCLS + c1] : trans[c1*NCLS + ka]) * LOG2E - nc1);
        float f1 = __builtin_amdgcn_exp2f((wid ? trans[kb*NCLS + c1] : trans[c1*NCLS + kb]) * LOG2E - nc1);
        a1u.u[j2] = rne_bf16(f0) | (rne_bf16(f1) << 16);
        float g0 = __builtin_amdgcn_exp2f((wid ? trans[ka*NCLS + c2] : trans[c2*NCLS + ka]) * LOG2E - nc2);
        float g1 = __builtin_amdgcn_exp2f((wid ? trans[kb*NCLS + c2] : trans[c2*NCLS + kb]) * LOG2E - nc2);
        a2u.u[j2] = rne_bf16(g0) | (rne_bf16(g1) << 16);
    }
    const short8 a1 = a1u.s, a2 = a2u.s;

    // ---- conversion biases for this lane's classes k0..k0+7 ----
    const float mtAx = mx_[k0+0] - 6.f, mtAy = mx_[k0+1] - 6.f;
    const float mtAz = mx_[k0+2] - 6.f, mtAw = mx_[k0+3] - 6.f;
    const float mtBx = mx_[k0+4] - 6.f, mtBy = mx_[k0+5] - 6.f;
    const float mtBz = mx_[k0+6] - 6.f, mtBw = mx_[k0+7] - 6.f;

    // ---- state init (identical for every batch column) ----
    float E1x = 0.f, E1y = 0.f, E1z = 0.f, E1w = 0.f;
    float E2x = 0.f, E2y = 0.f, E2z = 0.f, E2w = 0.f;
    if (wid == 0) {
        if (q == 3) E2z = 1.0f;       // SOS = 30 = 8*3+6
    } else {
        E1x = __builtin_amdgcn_exp2f(trans[EOS*NCLS + k0+0] * LOG2E - mx_[k0+0]);
        E1y = __builtin_amdgcn_exp2f(trans[EOS*NCLS + k0+1] * LOG2E - mx_[k0+1]);
        E1z = __builtin_amdgcn_exp2f(trans[EOS*NCLS + k0+2] * LOG2E - mx_[k0+2]);
        E1w = __builtin_amdgcn_exp2f(trans[EOS*NCLS + k0+3] * LOG2E - mx_[k0+3]);
        E2x = __builtin_amdgcn_exp2f(trans[EOS*NCLS + k0+4] * LOG2E - mx_[k0+4]);
        E2y = __builtin_amdgcn_exp2f(trans[EOS*NCLS + k0+5] * LOG2E - mx_[k0+5]);
        E2z = __builtin_amdgcn_exp2f(trans[EOS*NCLS + k0+6] * LOG2E - mx_[k0+6]);
        E2w = __builtin_amdgcn_exp2f(trans[EOS*NCLS + k0+7] * LOG2E - mx_[k0+7]);
    }
    float C = 0.f, cnt = 0.f;

    // ---- direction setup ----
    const long long fstep = (long long)B * NCLS;
    const int Hf = (S + 1) >> 1;
    const int H  = wid ? (S - Hf) : Hf;
    const int r0 = wid ? (S - 1) : 0;
    const long long dstep = wid ? -fstep : fstep;
    const long long mstep = wid ? -(long long)B : (long long)B;
    const int Hm1 = H - 1;
    const uint32_t dstepB = (uint32_t)(int)(dstep * 4);
    const uint32_t mstepB = (uint32_t)(int)(mstep * 4);
    // 32-bit byte offsets (arrays < 2GB; offsets stay >= 0 in both directions)
    uint32_t vofF = (uint32_t)(((long long)r0 * fstep + (long long)bb * NCLS + k0) * 4);
    uint32_t vofM = (uint32_t)(((long long)r0 * B + bb) * 4);

    // ---- prefetch ring: 8 named slots, 3 inline-asm loads each ----
    f32x4 sf1_0, sf1_1, sf1_2, sf1_3, sf1_4, sf1_5, sf1_6, sf1_7;
    f32x4 sf2_0, sf2_1, sf2_2, sf2_3, sf2_4, sf2_5, sf2_6, sf2_7;
    float sm_0, sm_1, sm_2, sm_3, sm_4, sm_5, sm_6, sm_7;

// EARLY-CLOBBER outputs: later instructions read %3/%5 after earlier outputs
// may have been written (async return) -> outputs must not alias any input.
#define ISSUE3(k, OF, OM)                                                    \
    asm volatile("global_load_dwordx4 %0, %3, %4\n\t"                        \
                 "global_load_dwordx4 %1, %3, %4 offset:16\n\t"              \
                 "global_load_dword %2, %5, %6"                              \
                 : "=&v"(sf1_##k), "=&v"(sf2_##k), "=&v"(sm_##k)             \
                 : "v"(OF), "s"(feats), "v"(OM), "s"(mask)                   \
                 : "memory");

#define WAITV21 { asm volatile("s_waitcnt vmcnt(21)" ::: "memory");          \
                  __builtin_amdgcn_sched_barrier(0); }

#define CONV(Rf1, Rf2, Rm, Ea, Eb, Md) {                                     \
        Ea.x = __builtin_amdgcn_exp2f(fmaf(Rf1.x, LOG2E, mtAx));             \
        Ea.y = __builtin_amdgcn_exp2f(fmaf(Rf1.y, LOG2E, mtAy));             \
        Ea.z = __builtin_amdgcn_exp2f(fmaf(Rf1.z, LOG2E, mtAz));             \
        Ea.w = __builtin_amdgcn_exp2f(fmaf(Rf1.w, LOG2E, mtAw));             \
        Eb.x = __builtin_amdgcn_exp2f(fmaf(Rf2.x, LOG2E, mtBx));             \
        Eb.y = __builtin_amdgcn_exp2f(fmaf(Rf2.y, LOG2E, mtBy));             \
        Eb.z = __builtin_amdgcn_exp2f(fmaf(Rf2.z, LOG2E, mtBz));             \
        Eb.w = __builtin_amdgcn_exp2f(fmaf(Rf2.w, LOG2E, mtBw));             \
        Md = Rm;                                                             \
    }

#define RENORM_E {                                                           \
        float _Dv = __shfl(E1x, n0, 64);      /* class 0 of this column */   \
        uint32_t _eb = (__float_as_uint(_Dv) >> 23) & 0xffu;                 \
        C += (float)((int)_eb - 127);                                        \
        float _sc = __uint_as_float((254u - _eb) << 23);                     \
        E1x *= _sc; E1y *= _sc; E1z *= _sc; E1w *= _sc;                      \
        E2x *= _sc; E2y *= _sc; E2z *= _sc; E2w *= _sc;                      \
    }

// fwd step: D = A*pack(E); E' = sel(ef .* D, E)
#define STEPF(EFa, EFb, EM, RN) {                                            \
        uint32_t p0 = __builtin_amdgcn_perm(__float_as_uint(E1y), __float_as_uint(E1x), 0x07060302u); \
        uint32_t p1 = __builtin_amdgcn_perm(__float_as_uint(E1w), __float_as_uint(E1z), 0x07060302u); \
        uint32_t p2 = __builtin_amdgcn_perm(__float_as_uint(E2y), __float_as_uint(E2x), 0x07060302u); \
        uint32_t p3 = __builtin_amdgcn_perm(__float_as_uint(E2w), __float_as_uint(E2z), 0x07060302u); \
        union { uint32_t u[4]; short8 s; } _bu;                              \
        _bu.u[0] = p0; _bu.u[1] = p1; _bu.u[2] = p2; _bu.u[3] = p3;          \
        const f32x4 _z = {0.f, 0.f, 0.f, 0.f};                               \
        f32x4 _d1 = __builtin_amdgcn_mfma_f32_16x16x32_bf16(a1, _bu.s, _z, 0, 0, 0); \
        f32x4 _d2 = __builtin_amdgcn_mfma_f32_16x16x32_bf16(a2, _bu.s, _z, 0, 0, 0); \
        const bool _s = (EM != 0.0f);                                        \
        E1x = _s ? _d1[0] * EFa.x : E1x;  E1y = _s ? _d1[1] * EFa.y : E1y;   \
        E1z = _s ? _d1[2] * EFa.z : E1z;  E1w = _s ? _d1[3] * EFa.w : E1w;   \
        E2x = _s ? _d2[0] * EFb.x : E2x;  E2y = _s ? _d2[1] * EFb.y : E2y;   \
        E2z = _s ? _d2[2] * EFb.z : E2z;  E2w = _s ? _d2[3] * EFb.w : E2w;   \
        cnt += EM;                                                           \
        if (RN) RENORM_E                                                     \
    }

// bwd step: t = ef .* w; D = A*pack(t); w' = sel(D, w)
#define STEPB(EFa, EFb, EM, RN) {                                            \
        float t1x = E1x * EFa.x, t1y = E1y * EFa.y, t1z = E1z * EFa.z, t1w = E1w * EFa.w; \
        float t2x = E2x * EFb.x, t2y = E2y * EFb.y, t2z = E2z * EFb.z, t2w = E2w * EFb.w; \
        uint32_t p0 = __builtin_amdgcn_perm(__float_as_uint(t1y), __float_as_uint(t1x), 0x07060302u); \
        uint32_t p1 = __builtin_amdgcn_perm(__float_as_uint(t1w), __float_as_uint(t1z), 0x07060302u); \
        uint32_t p2 = __builtin_amdgcn_perm(__float_as_uint(t2y), __float_as_uint(t2x), 0x07060302u); \
        uint32_t p3 = __builtin_amdgcn_perm(__float_as_uint(t2w), __float_as_uint(t2z), 0x07060302u); \
        union { uint32_t u[4]; short8 s; } _bu;                              \
        _bu.u[0] = p0; _bu.u[1] = p1; _bu.u[2] = p2; _bu.u[3] = p3;          \
        const f32x4 _z = {0.f, 0.f, 0.f, 0.f};                               \
        f32x4 _d1 = __builtin_amdgcn_mfma_f32_16x16x32_bf16(a1, _bu.s, _z, 0, 0, 0); \
        f32x4 _d2 = __builtin_amdgcn_mfma_f32_16x16x32_bf16(a2, _bu.s, _z, 0, 0, 0); \
        const bool _s = (EM != 0.0f);                                        \
        E1x = _s ? _d1[0] : E1x;  E1y = _s ? _d1[1] : E1y;                   \
        E1z = _s ? _d1[2] : E1z;  E1w = _s ? _d1[3] : E1w;                   \
        E2x = _s ? _d2[0] : E2x;  E2y = _s ? _d2[1] : E2y;                   \
        E2z = _s ? _d2[2] : E2z;  E2w = _s ? _d2[3] : E2w;                   \
        cnt += EM;                                                           \
        if (RN) RENORM_E                                                     \
    }

// steady step: wait oldest slot done -> consume -> reissue slot at time
// stageT = min(t+k+8, H-1) -> scalar-guarded pointer advance
#define GSTEP(k, RN, STEPM) {                                                \
        WAITV21                                                              \
        f32x4 e1, e2; float em;                                              \
        CONV(sf1_##k, sf2_##k, sm_##k, e1, e2, em);                          \
        STEPM(e1, e2, em, RN)                                                \
        ISSUE3(k, pfF, pfM)                                                  \
        { const uint32_t _a = (stageT < Hm1) ? 1u : 0u;                      \
          pfF += _a ? dstepB : 0u;                                           \
          pfM += _a ? mstepB : 0u;                                           \
          stageT += (int)_a; }                                               \
    }

// tail step (no reissue): wait count drops by 3 per consumed slot
#define TSTEP(k, VMC, STEPM)                                                 \
    if (t + k < H) {                                                         \
        asm volatile("s_waitcnt vmcnt(" #VMC ")" ::: "memory");              \
        __builtin_amdgcn_sched_barrier(0);                                   \
        f32x4 e1, e2; float em;                                              \
        CONV(sf1_##k, sf2_##k, sm_##k, e1, e2, em);                          \
        STEPM(e1, e2, em, true)                                              \
    }

#define PROI(k) ISSUE3(k, oF, oM)                                            \
    if (k < Hm1) { oF += dstepB; oM += mstepB; }

#define PIPELINE(STEPM) {                                                    \
        uint32_t oF = vofF, oM = vofM;                                       \
        PROI(0) PROI(1) PROI(2) PROI(3) PROI(4) PROI(5) PROI(6) PROI(7)      \
        uint32_t pfF = oF, pfM = oM;                                         \
        int stageT = (Hm1 < 8) ? Hm1 : 8;                                    \
        int t = 0;                                                           \
        for (; t + 8 <= H; t += 8) {                                         \
            GSTEP(0, false, STEPM) GSTEP(1, false, STEPM)                    \
            GSTEP(2, false, STEPM) GSTEP(3, true,  STEPM)                    \
            GSTEP(4, false, STEPM) GSTEP(5, false, STEPM)                    \
            GSTEP(6, false, STEPM) GSTEP(7, true,  STEPM)                    \
        }                                                                    \
        TSTEP(0, 21, STEPM) TSTEP(1, 18, STEPM) TSTEP(2, 15, STEPM)          \
        TSTEP(3, 12, STEPM) TSTEP(4, 9,  STEPM) TSTEP(5, 6,  STEPM)          \
        TSTEP(6, 3,  STEPM)                                                  \
        asm volatile("s_waitcnt vmcnt(0)" ::: "memory");                     \
        __builtin_amdgcn_sched_barrier(0);                                   \
    }

    if (H > 0) {
        if (wid == 0) { PIPELINE(STEPF) } else { PIPELINE(STEPB) }
    }

    // ---- combine: bwd publishes wtil*2^cms + scalar; fwd dots with E ----
    if (wid == 1) {
        wsh[n0][k0+0] = E1x * __builtin_amdgcn_exp2f(mx_[k0+0]);
        wsh[n0][k0+1] = E1y * __builtin_amdgcn_exp2f(mx_[k0+1]);
        wsh[n0][k0+2] = E1z * __builtin_amdgcn_exp2f(mx_[k0+2]);
        wsh[n0][k0+3] = E1w * __builtin_amdgcn_exp2f(mx_[k0+3]);
        wsh[n0][k0+4] = E2x * __builtin_amdgcn_exp2f(mx_[k0+4]);
        wsh[n0][k0+5] = E2y * __builtin_amdgcn_exp2f(mx_[k0+5]);
        wsh[n0][k0+6] = E2z * __builtin_amdgcn_exp2f(mx_[k0+6]);
        wsh[n0][k0+7] = E2w * __builtin_amdgcn_exp2f(mx_[k0+7]);
        if (q == 0) wsc[n0] = C + 6.0f * cnt;
    }
    __syncthreads();
    if (wid == 0) {
        const f32x4 wa = *(const f32x4*)&wsh[n0][k0];
        const f32x4 wb = *(const f32x4*)&wsh[n0][k0 + 4];
        float dot = E1x * wa.x + E1y * wa.y + E1z * wa.z + E1w * wa.w
                  + E2x * wb.x + E2y * wb.y + E2z * wb.z + E2w * wb.w;
        dot += __shfl_xor(dot, 16, 64);
        dot += __shfl_xor(dot, 32, 64);
        if (q == 0 && b < B) {
            out[b] = LN2 * (C + 6.0f * cnt + wsc[n0] + __builtin_amdgcn_logf(dot));
        }
    }
#undef ISSUE3
#undef WAITV21
#undef CONV
#undef RENORM_E
#undef STEPF
#undef STEPB
#undef GSTEP
#undef TSTEP
#undef PROI
#undef PIPELINE
}

extern "C" void kernel_launch(void* const* d_in, const int* in_sizes, int n_in,
                              void* d_out, int out_size, void* d_ws, size_t ws_size,
                              hipStream_t stream) {
    const float* feats = (const float*)d_in[0];
    const float* mask  = (const float*)d_in[1];
    const float* trans = (const float*)d_in[2];
    float* out = (float*)d_out;

    const int B = out_size;            // batch  (2048)
    const int S = in_sizes[1] / B;     // seq_len (512)

    dim3 block(128);                   // wave 0 = fwd, wave 1 = bwd
    dim3 grid((B + 15) / 16);          // 16 real batches per block -> 128 blocks
    hipLaunchKernelGGL(crf_fwd, grid, block, 0, stream, feats, mask, trans, out, S, B);
}